// Round 5
// baseline (90.655 us; speedup 1.0000x reference)
//
#include <hip/hip_runtime.h>

// YOLO loss: N=8192, S=14, B=2, C=20. ncells = N*S*S = 1,605,632.
// d_in[0] pred (ncells*30 f32), d_in[1] tbox (ncells*4 f32),
// d_in[2] tcls (ncells*20 f32), d_in[3] mask (ncells, dtype detected at runtime)
// d_out: 5 f32 = [total, reg, contain, noobj, cls] / N
//
// R5: occupancy attack. LDS 30.7KB -> 12.4KB/block:
//  - box words (j<10) staged to sbox[256][11] (pad -> conflict-free)
//  - cls words (j>=10) consumed STREAMING during the staging pass,
//    tcls load predicated on f[cell]!=0 (keeps sparse-line traffic)
//  - f / tbox coalesced in phase 0, tbox held in registers
// Epilogue: per-block float4 partial + reduce kernel (R4, no contended atomics).

#define L_COORD 5.0f
#define L_NOOBJ 0.5f
#define TILE 256

// ws layout: int flag at byte 512; float4 partials[ntiles] at byte 1024.

__global__ void detect_mask_kernel(const unsigned int* __restrict__ w, int nwords,
                                   int* __restrict__ flag) {
    __shared__ int s_int, s_flt;
    if (threadIdx.x == 0) { s_int = 1; s_flt = 1; }
    __syncthreads();
    int okInt = 1, okFlt = 1;
    for (int i = threadIdx.x; i < nwords; i += blockDim.x) {
        unsigned int v = w[i];
        okInt = okInt && (v == 0u || v == 1u);
        okFlt = okFlt && (v == 0u || v == 0x3F800000u);
    }
    if (!okInt) atomicAnd(&s_int, 0);
    if (!okFlt) atomicAnd(&s_flt, 0);
    __syncthreads();
    if (threadIdx.x == 0) *flag = s_int ? 1 : (s_flt ? 2 : 0);
}

__launch_bounds__(256)
__global__ void yolo_loss_kernel(const float* __restrict__ pred,
                                 const float* __restrict__ tbox,
                                 const float* __restrict__ tcls,
                                 const void* __restrict__ mask,
                                 const int* __restrict__ flag_p,
                                 float4* __restrict__ partials,
                                 int ncells) {
    __shared__ float sf[TILE];                 // 1 KB: f per cell
    __shared__ float sbox[TILE * 11];          // 11.25 KB: 10 box words, stride 11
    __shared__ float red[4][4];

    const int flg = *flag_p;                   // uniform
    const float invS = 1.0f / 14.0f;
    const unsigned tid = threadIdx.x;

    const int tile = blockIdx.x;
    const size_t base = (size_t)tile * TILE;
    int nvalid = ncells - (int)base;
    if (nvalid > TILE) nvalid = TILE;

    // ---- phase 0: coalesced f + tbox for my cell ----
    float f = 0.0f;
    float4 tb = make_float4(0.f, 0.f, 0.f, 0.f);
    if ((int)tid < nvalid) {
        const size_t c = base + tid;
        if (flg == 1)      f = (((const int*)mask)[c] != 0) ? 1.0f : 0.0f;
        else if (flg == 2) f = ((const float*)mask)[c];
        else               f = (((const unsigned char*)mask)[c] != 0) ? 1.0f : 0.0f;
        tb = ((const float4*)tbox)[c];
    }
    sf[tid] = f;
    __syncthreads();

    // ---- phase 1: stream pred tile; box words -> LDS, cls words -> a_cls ----
    float a_cls = 0.f;
    {
        const float4* gp4 = (const float4*)(pred + base * 30);
        const float* tcp = tcls + base * 20;
        const int nv30 = nvalid * 30;          // total valid words in tile
        #pragma unroll
        for (int i = 0; i < 8; ++i) {
            int q = (int)tid + (i << 8);
            int w0 = q << 2;
            if (w0 + 3 < nv30) {
                float4 v = gp4[q];
                int c0 = (unsigned)w0 / 30u;
                int j0 = w0 - 30 * c0;
                float vv[4] = {v.x, v.y, v.z, v.w};
                #pragma unroll
                for (int e = 0; e < 4; ++e) {
                    int j = j0 + e;
                    int roll = (j >= 30);
                    int cc = c0 + roll;
                    j -= 30 * roll;
                    if (j < 10) {
                        sbox[cc * 11 + j] = vv[e];
                    } else {
                        float fv = sf[cc];
                        if (fv != 0.0f) {
                            float t = tcp[cc * 20 + (j - 10)];
                            float d = vv[e] - t;
                            a_cls += fv * d * d;
                        }
                    }
                }
            } else if (w0 < nv30) {            // partial-tile tail (not hit at 8192)
                #pragma unroll
                for (int e = 0; e < 4; ++e) {
                    int w = w0 + e;
                    if (w < nv30) {
                        float ve = pred[base * 30 + w];
                        int cc = (unsigned)w / 30u;
                        int j = w - 30 * cc;
                        if (j < 10) {
                            sbox[cc * 11 + j] = ve;
                        } else {
                            float fv = sf[cc];
                            if (fv != 0.0f) {
                                float t = tcp[cc * 20 + (j - 10)];
                                float d = ve - t;
                                a_cls += fv * d * d;
                            }
                        }
                    }
                }
            }
        }
    }
    __syncthreads();

    // ---- phase 2: per-cell box math from LDS ----
    float a_reg = 0.f, a_con = 0.f, a_noo = 0.f;
    if ((int)tid < nvalid) {
        const float* my = sbox + tid * 11;
        float px0 = my[0], py0 = my[1], pw0 = my[2], ph0 = my[3], cf0 = my[4];
        float px1 = my[5], py1 = my[6], pw1 = my[7], ph1 = my[8], cf1 = my[9];

        a_noo = (1.0f - f) * (cf0 * cf0 + cf1 * cf1);

        if (f != 0.0f) {
            float tx1 = tb.x * invS - 0.5f * tb.z;
            float ty1 = tb.y * invS - 0.5f * tb.w;
            float tx2 = tb.x * invS + 0.5f * tb.z;
            float ty2 = tb.y * invS + 0.5f * tb.w;
            float ta  = (tx2 - tx1) * (ty2 - ty1);

            // IoU box 0
            float x1 = px0 * invS - 0.5f * pw0, y1 = py0 * invS - 0.5f * ph0;
            float x2 = px0 * invS + 0.5f * pw0, y2 = py0 * invS + 0.5f * ph0;
            float lx = fmaxf(x1, tx1), ly = fmaxf(y1, ty1);
            float rx = fminf(x2, tx2), ry = fminf(y2, ty2);
            float wx = fmaxf(rx - lx, 0.f), wy = fmaxf(ry - ly, 0.f);
            float inter = wx * wy;
            float pa = (x2 - x1) * (y2 - y1);
            float iou0 = inter / (pa + ta - inter);
            // IoU box 1
            x1 = px1 * invS - 0.5f * pw1; y1 = py1 * invS - 0.5f * ph1;
            x2 = px1 * invS + 0.5f * pw1; y2 = py1 * invS + 0.5f * ph1;
            lx = fmaxf(x1, tx1); ly = fmaxf(y1, ty1);
            rx = fminf(x2, tx2); ry = fminf(y2, ty2);
            wx = fmaxf(rx - lx, 0.f); wy = fmaxf(ry - ly, 0.f);
            inter = wx * wy;
            pa = (x2 - x1) * (y2 - y1);
            float iou1 = inter / (pa + ta - inter);

            // jnp.argmax: first index on tie -> box1 wins only if strictly greater
            int best = (iou1 > iou0) ? 1 : 0;
            float miou = fmaxf(iou0, iou1);

            float bx = best ? px1 : px0, by = best ? py1 : py0;
            float bw = best ? pw1 : pw0, bh = best ? ph1 : ph0;
            float bc = best ? cf1 : cf0;

            float dx = bx - tb.x, dy = by - tb.y;
            float sw = sqrtf(fmaxf(bw, 0.f)) - sqrtf(fmaxf(tb.z, 0.f));
            float sh = sqrtf(fmaxf(bh, 0.f)) - sqrtf(fmaxf(tb.w, 0.f));
            a_reg = f * (dx * dx + dy * dy + sw * sw + sh * sh);
            float dc = bc - miou;
            a_con = f * dc * dc;
        }
    }

    // ---- wave reduce, block reduce, ONE uncontended partial store ----
    #pragma unroll
    for (int off = 32; off > 0; off >>= 1) {
        a_reg += __shfl_down(a_reg, off, 64);
        a_con += __shfl_down(a_con, off, 64);
        a_noo += __shfl_down(a_noo, off, 64);
        a_cls += __shfl_down(a_cls, off, 64);
    }
    const int wid = threadIdx.x >> 6, lane = threadIdx.x & 63;
    if (lane == 0) {
        red[wid][0] = a_reg; red[wid][1] = a_con;
        red[wid][2] = a_noo; red[wid][3] = a_cls;
    }
    __syncthreads();
    if (threadIdx.x == 0) {
        float rg = 0.f, co = 0.f, no = 0.f, cl = 0.f;
        #pragma unroll
        for (int w = 0; w < 4; ++w) {
            rg += red[w][0]; co += red[w][1]; no += red[w][2]; cl += red[w][3];
        }
        partials[blockIdx.x] = make_float4(rg, co, no, cl);
    }
}

__launch_bounds__(256)
__global__ void reduce_kernel(const float4* __restrict__ partials, int nblocks,
                              float* __restrict__ out, float inv_n) {
    __shared__ float red[4][4];
    float rg = 0.f, co = 0.f, no = 0.f, cl = 0.f;
    for (int i = threadIdx.x; i < nblocks; i += blockDim.x) {
        float4 p = partials[i];
        rg += p.x; co += p.y; no += p.z; cl += p.w;
    }
    #pragma unroll
    for (int off = 32; off > 0; off >>= 1) {
        rg += __shfl_down(rg, off, 64);
        co += __shfl_down(co, off, 64);
        no += __shfl_down(no, off, 64);
        cl += __shfl_down(cl, off, 64);
    }
    const int wid = threadIdx.x >> 6, lane = threadIdx.x & 63;
    if (lane == 0) { red[wid][0] = rg; red[wid][1] = co; red[wid][2] = no; red[wid][3] = cl; }
    __syncthreads();
    if (threadIdx.x == 0) {
        float r = 0.f, c2 = 0.f, n2 = 0.f, c3 = 0.f;
        #pragma unroll
        for (int w = 0; w < 4; ++w) { r += red[w][0]; c2 += red[w][1]; n2 += red[w][2]; c3 += red[w][3]; }
        float total = c3 + L_NOOBJ * n2 + L_COORD * r + c2;
        out[0] = total * inv_n;
        out[1] = r  * inv_n;
        out[2] = c2 * inv_n;
        out[3] = n2 * inv_n;
        out[4] = c3 * inv_n;
    }
}

extern "C" void kernel_launch(void* const* d_in, const int* in_sizes, int n_in,
                              void* d_out, int out_size, void* d_ws, size_t ws_size,
                              hipStream_t stream) {
    const float* pred = (const float*)d_in[0];
    const float* tbox = (const float*)d_in[1];
    const float* tcls = (const float*)d_in[2];
    const void*  mask = d_in[3];
    const int ncells = in_sizes[3];            // N*S*S
    const int N = ncells / (14 * 14);
    const int ntiles = (ncells + TILE - 1) / TILE;   // 6272

    int*    flag     = (int*)((char*)d_ws + 512);
    float4* partials = (float4*)((char*)d_ws + 1024);

    int nwords = ((ncells < 16384) ? ncells : 16384) / 4;
    detect_mask_kernel<<<1, 256, 0, stream>>>((const unsigned int*)mask, nwords, flag);

    yolo_loss_kernel<<<ntiles, 256, 0, stream>>>(pred, tbox, tcls, mask, flag,
                                                 partials, ncells);

    reduce_kernel<<<1, 256, 0, stream>>>(partials, ntiles, (float*)d_out, 1.0f / (float)N);
}

// Round 6
// 57.786 us; speedup vs baseline: 1.5688x; 1.5688x over previous
//
#include <hip/hip_runtime.h>

// YOLO loss: N=8192, S=14, B=2, C=20. ncells = N*S*S = 1,605,632.
// d_in[0] pred (ncells*30 f32), d_in[1] tbox (ncells*4 f32),
// d_in[2] tcls (ncells*20 f32), d_in[3] mask (ncells, dtype detected at runtime)
// d_out: 5 f32 = [total, reg, contain, noobj, cls] / N
//
// R6: no-LDS no-barrier gather design. Each thread owns one cell.
// Misaligned 120B rows handled by aligned float4 loads + cndmask unpack
// (row_byte % 16 is always 0 or 8 -> word shift 0 or 2).
// cls/tbox/tcls loads predicated on f!=0 (~15% of lanes).
// Epilogue: per-block float4 partial + reduce kernel (R4, proven).

#define L_COORD 5.0f
#define L_NOOBJ 0.5f
#define TILE 256

// ws layout: int flag at byte 512; float4 partials[ntiles] at byte 1024.

__global__ void detect_mask_kernel(const unsigned int* __restrict__ w, int nwords,
                                   int* __restrict__ flag) {
    __shared__ int s_int, s_flt;
    if (threadIdx.x == 0) { s_int = 1; s_flt = 1; }
    __syncthreads();
    int okInt = 1, okFlt = 1;
    for (int i = threadIdx.x; i < nwords; i += blockDim.x) {
        unsigned int v = w[i];
        okInt = okInt && (v == 0u || v == 1u);
        okFlt = okFlt && (v == 0u || v == 0x3F800000u);
    }
    if (!okInt) atomicAnd(&s_int, 0);
    if (!okFlt) atomicAnd(&s_flt, 0);
    __syncthreads();
    if (threadIdx.x == 0) *flag = s_int ? 1 : (s_flt ? 2 : 0);
}

__launch_bounds__(256)
__global__ void yolo_loss_kernel(const float* __restrict__ pred,
                                 const float* __restrict__ tbox,
                                 const float* __restrict__ tcls,
                                 const void* __restrict__ mask,
                                 const int* __restrict__ flag_p,
                                 float4* __restrict__ partials,
                                 int ncells) {
    __shared__ float red[4][4];

    const int flg = *flag_p;                   // uniform
    const float invS = 1.0f / 14.0f;
    const unsigned tid = threadIdx.x;
    const unsigned c = blockIdx.x * TILE + tid;

    float a_reg = 0.f, a_con = 0.f, a_noo = 0.f, a_cls = 0.f;

    if (c < (unsigned)ncells) {
        float f;
        if (flg == 1)      f = (((const int*)mask)[c] != 0) ? 1.0f : 0.0f;
        else if (flg == 2) f = ((const float*)mask)[c];
        else               f = (((const unsigned char*)mask)[c] != 0) ? 1.0f : 0.0f;

        // ---- box words j0..j9 via aligned float4 + unpack ----
        unsigned off = c * 120u;               // row start byte (fits 32b: <193M)
        unsigned a   = off & ~15u;             // 16B-aligned base; off-a in {0,8}
        bool s2 = (off != a);                  // shift 2 words if misaligned
        const float4* pa4 = (const float4*)((const char*)pred + a);
        float4 q0 = pa4[0], q1 = pa4[1], q2 = pa4[2];   // covers bytes [a, a+48)

        float px0 = s2 ? q0.z : q0.x;
        float py0 = s2 ? q0.w : q0.y;
        float pw0 = s2 ? q1.x : q0.z;
        float ph0 = s2 ? q1.y : q0.w;
        float cf0 = s2 ? q1.z : q1.x;
        float px1 = s2 ? q1.w : q1.y;
        float py1 = s2 ? q2.x : q1.z;
        float pw1 = s2 ? q2.y : q1.w;
        float ph1 = s2 ? q2.z : q2.x;
        float cf1 = s2 ? q2.w : q2.y;

        a_noo = (1.0f - f) * (cf0 * cf0 + cf1 * cf1);

        if (f != 0.0f) {                       // ~15% of lanes
            // ---- cls words k0..k19 via aligned float4 + unpack ----
            unsigned off2 = off + 40u;         // cls region start byte
            unsigned a2   = off2 & ~15u;       // off2-a2 in {8 (c even), 0 (c odd)}
            bool s2c = (off2 != a2);           // shift 2 words
            const float4* ca4 = (const float4*)((const char*)pred + a2);
            float W[22];
            {
                float4 u0 = ca4[0], u1 = ca4[1], u2 = ca4[2], u3 = ca4[3], u4 = ca4[4];
                W[0]=u0.x; W[1]=u0.y; W[2]=u0.z; W[3]=u0.w;
                W[4]=u1.x; W[5]=u1.y; W[6]=u1.z; W[7]=u1.w;
                W[8]=u2.x; W[9]=u2.y; W[10]=u2.z; W[11]=u2.w;
                W[12]=u3.x; W[13]=u3.y; W[14]=u3.z; W[15]=u3.w;
                W[16]=u4.x; W[17]=u4.y; W[18]=u4.z; W[19]=u4.w;
                W[20] = 0.f; W[21] = 0.f;
                if (s2c) {                     // need words 20,21 (bytes a2+80..88, within row)
                    float2 e = *(const float2*)((const char*)pred + a2 + 80u);
                    W[20] = e.x; W[21] = e.y;
                }
            }

            const float4* tc4 = (const float4*)((const char*)tcls + c * 80u);
            float cl = 0.f;
            #pragma unroll
            for (int i = 0; i < 5; ++i) {
                float4 t = tc4[i];
                float p0 = s2c ? W[4*i+2] : W[4*i+0];
                float p1 = s2c ? W[4*i+3] : W[4*i+1];
                float p2 = s2c ? W[4*i+4] : W[4*i+2];
                float p3 = s2c ? W[4*i+5] : W[4*i+3];
                float d0 = p0 - t.x, d1 = p1 - t.y, d2 = p2 - t.z, d3 = p3 - t.w;
                cl += d0 * d0 + d1 * d1 + d2 * d2 + d3 * d3;
            }
            a_cls = f * cl;

            float4 tb = *(const float4*)((const char*)tbox + c * 16u);
            float tx1 = tb.x * invS - 0.5f * tb.z;
            float ty1 = tb.y * invS - 0.5f * tb.w;
            float tx2 = tb.x * invS + 0.5f * tb.z;
            float ty2 = tb.y * invS + 0.5f * tb.w;
            float ta  = (tx2 - tx1) * (ty2 - ty1);

            // IoU box 0
            float x1 = px0 * invS - 0.5f * pw0, y1 = py0 * invS - 0.5f * ph0;
            float x2 = px0 * invS + 0.5f * pw0, y2 = py0 * invS + 0.5f * ph0;
            float lx = fmaxf(x1, tx1), ly = fmaxf(y1, ty1);
            float rx = fminf(x2, tx2), ry = fminf(y2, ty2);
            float wx = fmaxf(rx - lx, 0.f), wy = fmaxf(ry - ly, 0.f);
            float inter = wx * wy;
            float pa = (x2 - x1) * (y2 - y1);
            float iou0 = inter / (pa + ta - inter);
            // IoU box 1
            x1 = px1 * invS - 0.5f * pw1; y1 = py1 * invS - 0.5f * ph1;
            x2 = px1 * invS + 0.5f * pw1; y2 = py1 * invS + 0.5f * ph1;
            lx = fmaxf(x1, tx1); ly = fmaxf(y1, ty1);
            rx = fminf(x2, tx2); ry = fminf(y2, ty2);
            wx = fmaxf(rx - lx, 0.f); wy = fmaxf(ry - ly, 0.f);
            inter = wx * wy;
            pa = (x2 - x1) * (y2 - y1);
            float iou1 = inter / (pa + ta - inter);

            // jnp.argmax: first index on tie -> box1 wins only if strictly greater
            int best = (iou1 > iou0) ? 1 : 0;
            float miou = fmaxf(iou0, iou1);

            float bx = best ? px1 : px0, by = best ? py1 : py0;
            float bw = best ? pw1 : pw0, bh = best ? ph1 : ph0;
            float bc = best ? cf1 : cf0;

            float dx = bx - tb.x, dy = by - tb.y;
            float sw = sqrtf(fmaxf(bw, 0.f)) - sqrtf(fmaxf(tb.z, 0.f));
            float sh = sqrtf(fmaxf(bh, 0.f)) - sqrtf(fmaxf(tb.w, 0.f));
            a_reg = f * (dx * dx + dy * dy + sw * sw + sh * sh);
            float dc = bc - miou;
            a_con = f * dc * dc;
        }
    }

    // ---- wave reduce, block reduce, ONE uncontended partial store ----
    #pragma unroll
    for (int off = 32; off > 0; off >>= 1) {
        a_reg += __shfl_down(a_reg, off, 64);
        a_con += __shfl_down(a_con, off, 64);
        a_noo += __shfl_down(a_noo, off, 64);
        a_cls += __shfl_down(a_cls, off, 64);
    }
    const int wid = threadIdx.x >> 6, lane = threadIdx.x & 63;
    if (lane == 0) {
        red[wid][0] = a_reg; red[wid][1] = a_con;
        red[wid][2] = a_noo; red[wid][3] = a_cls;
    }
    __syncthreads();
    if (threadIdx.x == 0) {
        float rg = 0.f, co = 0.f, no = 0.f, cl = 0.f;
        #pragma unroll
        for (int w = 0; w < 4; ++w) {
            rg += red[w][0]; co += red[w][1]; no += red[w][2]; cl += red[w][3];
        }
        partials[blockIdx.x] = make_float4(rg, co, no, cl);
    }
}

__launch_bounds__(256)
__global__ void reduce_kernel(const float4* __restrict__ partials, int nblocks,
                              float* __restrict__ out, float inv_n) {
    __shared__ float red[4][4];
    float rg = 0.f, co = 0.f, no = 0.f, cl = 0.f;
    for (int i = threadIdx.x; i < nblocks; i += blockDim.x) {
        float4 p = partials[i];
        rg += p.x; co += p.y; no += p.z; cl += p.w;
    }
    #pragma unroll
    for (int off = 32; off > 0; off >>= 1) {
        rg += __shfl_down(rg, off, 64);
        co += __shfl_down(co, off, 64);
        no += __shfl_down(no, off, 64);
        cl += __shfl_down(cl, off, 64);
    }
    const int wid = threadIdx.x >> 6, lane = threadIdx.x & 63;
    if (lane == 0) { red[wid][0] = rg; red[wid][1] = co; red[wid][2] = no; red[wid][3] = cl; }
    __syncthreads();
    if (threadIdx.x == 0) {
        float r = 0.f, c2 = 0.f, n2 = 0.f, c3 = 0.f;
        #pragma unroll
        for (int w = 0; w < 4; ++w) { r += red[w][0]; c2 += red[w][1]; n2 += red[w][2]; c3 += red[w][3]; }
        float total = c3 + L_NOOBJ * n2 + L_COORD * r + c2;
        out[0] = total * inv_n;
        out[1] = r  * inv_n;
        out[2] = c2 * inv_n;
        out[3] = n2 * inv_n;
        out[4] = c3 * inv_n;
    }
}

extern "C" void kernel_launch(void* const* d_in, const int* in_sizes, int n_in,
                              void* d_out, int out_size, void* d_ws, size_t ws_size,
                              hipStream_t stream) {
    const float* pred = (const float*)d_in[0];
    const float* tbox = (const float*)d_in[1];
    const float* tcls = (const float*)d_in[2];
    const void*  mask = d_in[3];
    const int ncells = in_sizes[3];            // N*S*S
    const int N = ncells / (14 * 14);
    const int ntiles = (ncells + TILE - 1) / TILE;   // 6272

    int*    flag     = (int*)((char*)d_ws + 512);
    float4* partials = (float4*)((char*)d_ws + 1024);

    int nwords = ((ncells < 16384) ? ncells : 16384) / 4;
    detect_mask_kernel<<<1, 256, 0, stream>>>((const unsigned int*)mask, nwords, flag);

    yolo_loss_kernel<<<ntiles, 256, 0, stream>>>(pred, tbox, tcls, mask, flag,
                                                 partials, ncells);

    reduce_kernel<<<1, 256, 0, stream>>>(partials, ntiles, (float*)d_out, 1.0f / (float)N);
}

// Round 7
// 56.667 us; speedup vs baseline: 1.5998x; 1.0197x over previous
//
#include <hip/hip_runtime.h>

// YOLO loss: N=8192, S=14, B=2, C=20. ncells = N*S*S = 1,605,632.
// d_in[0] pred (ncells*30 f32), d_in[1] tbox (ncells*4 f32),
// d_in[2] tcls (ncells*20 f32), d_in[3] mask (ncells, dtype detected per block)
// d_out: 5 f32 = [total, reg, contain, noobj, cls] / N
//
// R7: two kernels only. Main kernel: per-block mask classification (no detect
// kernel), 4 cells/thread in a contiguous 1024-cell chunk (ncells=1568*1024),
// R6 aligned-float4+cndmask gather core, per-block partial. Reduce: 25KB, L2-hot.

#define L_COORD 5.0f
#define L_NOOBJ 0.5f
#define BLK 256
#define CPT 4
#define CHUNK (BLK * CPT)   // 1024 cells per block

__launch_bounds__(256)
__global__ void yolo_loss_kernel(const float* __restrict__ pred,
                                 const float* __restrict__ tbox,
                                 const float* __restrict__ tcls,
                                 const void* __restrict__ mask,
                                 float4* __restrict__ partials,
                                 int ncells) {
    __shared__ float red[4][4];
    __shared__ int s_vote;

    const float invS = 1.0f / 14.0f;
    const unsigned tid = threadIdx.x;
    const unsigned base = blockIdx.x * CHUNK;
    const unsigned int* mw = (const unsigned int*)mask;

    // ---- per-block mask dtype classification ----
    // word path (int32 {0,1} OR float {0,1.0f}): f = (word != 0)
    // byte path: bytes in {0,1}, evidence = any byte-lane 1..3 set
    if (tid == 0) s_vote = 0;
    __syncthreads();
    {
        int maxw = (ncells >> 2) - 64;         // valid under byte interp too
        int ws = (int)(base >> 2);
        if (ws > maxw) ws = maxw;
        if (ws < 0) ws = 0;
        unsigned v = mw[ws + (tid & 63)];
        bool byteEvid = ((v & 0x01010100u) != 0u) && ((v & ~0x01010101u) == 0u);
        if (byteEvid) atomicOr(&s_vote, 1);
    }
    __syncthreads();
    const bool isByte = (s_vote & 1);

    float a_reg = 0.f, a_con = 0.f, a_noo = 0.f, a_cls = 0.f;

    // ---- load phase: masks + box regions for 4 cells (deep MLP) ----
    float fm[CPT];
    float4 q0[CPT], q1[CPT], q2[CPT];
    bool s2[CPT], valid[CPT];
    #pragma unroll
    for (int k = 0; k < CPT; ++k) {
        unsigned c = base + tid + k * BLK;
        valid[k] = (c < (unsigned)ncells);
        unsigned cs = valid[k] ? c : 0u;
        if (isByte) fm[k] = (((const unsigned char*)mask)[cs] != 0) ? 1.0f : 0.0f;
        else        fm[k] = (mw[cs] != 0u) ? 1.0f : 0.0f;
        unsigned off = cs * 120u;
        unsigned a = off & ~15u;
        s2[k] = (off != a);
        const float4* pa4 = (const float4*)((const char*)pred + a);
        q0[k] = pa4[0]; q1[k] = pa4[1]; q2[k] = pa4[2];
    }

    // ---- process 4 cells ----
    #pragma unroll
    for (int k = 0; k < CPT; ++k) {
        if (!valid[k]) continue;
        unsigned c = base + tid + k * BLK;
        float f = fm[k];
        bool sh = s2[k];

        float px0 = sh ? q0[k].z : q0[k].x;
        float py0 = sh ? q0[k].w : q0[k].y;
        float pw0 = sh ? q1[k].x : q0[k].z;
        float ph0 = sh ? q1[k].y : q0[k].w;
        float cf0 = sh ? q1[k].z : q1[k].x;
        float px1 = sh ? q1[k].w : q1[k].y;
        float py1 = sh ? q2[k].x : q1[k].z;
        float pw1 = sh ? q2[k].y : q1[k].w;
        float ph1 = sh ? q2[k].z : q2[k].x;
        float cf1 = sh ? q2[k].w : q2[k].y;

        a_noo += (1.0f - f) * (cf0 * cf0 + cf1 * cf1);

        if (f != 0.0f) {                       // ~15% of lanes
            unsigned off = c * 120u;
            unsigned off2 = off + 40u;
            unsigned a2 = off2 & ~15u;
            bool s2c = (off2 != a2);
            const float4* ca4 = (const float4*)((const char*)pred + a2);
            float W[22];
            {
                float4 u0 = ca4[0], u1 = ca4[1], u2 = ca4[2], u3 = ca4[3], u4 = ca4[4];
                W[0]=u0.x; W[1]=u0.y; W[2]=u0.z; W[3]=u0.w;
                W[4]=u1.x; W[5]=u1.y; W[6]=u1.z; W[7]=u1.w;
                W[8]=u2.x; W[9]=u2.y; W[10]=u2.z; W[11]=u2.w;
                W[12]=u3.x; W[13]=u3.y; W[14]=u3.z; W[15]=u3.w;
                W[16]=u4.x; W[17]=u4.y; W[18]=u4.z; W[19]=u4.w;
                W[20] = 0.f; W[21] = 0.f;
                if (s2c) {
                    float2 e = *(const float2*)((const char*)pred + a2 + 80u);
                    W[20] = e.x; W[21] = e.y;
                }
            }

            const float4* tc4 = (const float4*)((const char*)tcls + c * 80u);
            float cl = 0.f;
            #pragma unroll
            for (int i = 0; i < 5; ++i) {
                float4 t = tc4[i];
                float p0 = s2c ? W[4*i+2] : W[4*i+0];
                float p1 = s2c ? W[4*i+3] : W[4*i+1];
                float p2 = s2c ? W[4*i+4] : W[4*i+2];
                float p3 = s2c ? W[4*i+5] : W[4*i+3];
                float d0 = p0 - t.x, d1 = p1 - t.y, d2 = p2 - t.z, d3 = p3 - t.w;
                cl += d0 * d0 + d1 * d1 + d2 * d2 + d3 * d3;
            }
            a_cls += f * cl;

            float4 tb = *(const float4*)((const char*)tbox + c * 16u);
            float tx1 = tb.x * invS - 0.5f * tb.z;
            float ty1 = tb.y * invS - 0.5f * tb.w;
            float tx2 = tb.x * invS + 0.5f * tb.z;
            float ty2 = tb.y * invS + 0.5f * tb.w;
            float ta  = (tx2 - tx1) * (ty2 - ty1);

            float x1 = px0 * invS - 0.5f * pw0, y1 = py0 * invS - 0.5f * ph0;
            float x2 = px0 * invS + 0.5f * pw0, y2 = py0 * invS + 0.5f * ph0;
            float lx = fmaxf(x1, tx1), ly = fmaxf(y1, ty1);
            float rx = fminf(x2, tx2), ry = fminf(y2, ty2);
            float wx = fmaxf(rx - lx, 0.f), wy = fmaxf(ry - ly, 0.f);
            float inter = wx * wy;
            float pa = (x2 - x1) * (y2 - y1);
            float iou0 = inter / (pa + ta - inter);

            x1 = px1 * invS - 0.5f * pw1; y1 = py1 * invS - 0.5f * ph1;
            x2 = px1 * invS + 0.5f * pw1; y2 = py1 * invS + 0.5f * ph1;
            lx = fmaxf(x1, tx1); ly = fmaxf(y1, ty1);
            rx = fminf(x2, tx2); ry = fminf(y2, ty2);
            wx = fmaxf(rx - lx, 0.f); wy = fmaxf(ry - ly, 0.f);
            inter = wx * wy;
            pa = (x2 - x1) * (y2 - y1);
            float iou1 = inter / (pa + ta - inter);

            // jnp.argmax: first index on tie -> box1 wins only if strictly greater
            int best = (iou1 > iou0) ? 1 : 0;
            float miou = fmaxf(iou0, iou1);

            float bx = best ? px1 : px0, by = best ? py1 : py0;
            float bw = best ? pw1 : pw0, bh = best ? ph1 : ph0;
            float bc = best ? cf1 : cf0;

            float dx = bx - tb.x, dy = by - tb.y;
            float sw = sqrtf(fmaxf(bw, 0.f)) - sqrtf(fmaxf(tb.z, 0.f));
            float sh2 = sqrtf(fmaxf(bh, 0.f)) - sqrtf(fmaxf(tb.w, 0.f));
            a_reg += f * (dx * dx + dy * dy + sw * sw + sh2 * sh2);
            float dc = bc - miou;
            a_con += f * dc * dc;
        }
    }

    // ---- wave reduce, block reduce, ONE uncontended partial store ----
    #pragma unroll
    for (int off = 32; off > 0; off >>= 1) {
        a_reg += __shfl_down(a_reg, off, 64);
        a_con += __shfl_down(a_con, off, 64);
        a_noo += __shfl_down(a_noo, off, 64);
        a_cls += __shfl_down(a_cls, off, 64);
    }
    const int wid = threadIdx.x >> 6, lane = threadIdx.x & 63;
    if (lane == 0) {
        red[wid][0] = a_reg; red[wid][1] = a_con;
        red[wid][2] = a_noo; red[wid][3] = a_cls;
    }
    __syncthreads();
    if (threadIdx.x == 0) {
        float rg = 0.f, co = 0.f, no = 0.f, cl = 0.f;
        #pragma unroll
        for (int w = 0; w < 4; ++w) {
            rg += red[w][0]; co += red[w][1]; no += red[w][2]; cl += red[w][3];
        }
        partials[blockIdx.x] = make_float4(rg, co, no, cl);
    }
}

__launch_bounds__(256)
__global__ void reduce_kernel(const float4* __restrict__ partials, int nblocks,
                              float* __restrict__ out, float inv_n) {
    __shared__ float red[4][4];
    float rg = 0.f, co = 0.f, no = 0.f, cl = 0.f;
    for (int i = threadIdx.x; i < nblocks; i += blockDim.x) {
        float4 p = partials[i];
        rg += p.x; co += p.y; no += p.z; cl += p.w;
    }
    #pragma unroll
    for (int off = 32; off > 0; off >>= 1) {
        rg += __shfl_down(rg, off, 64);
        co += __shfl_down(co, off, 64);
        no += __shfl_down(no, off, 64);
        cl += __shfl_down(cl, off, 64);
    }
    const int wid = threadIdx.x >> 6, lane = threadIdx.x & 63;
    if (lane == 0) { red[wid][0] = rg; red[wid][1] = co; red[wid][2] = no; red[wid][3] = cl; }
    __syncthreads();
    if (threadIdx.x == 0) {
        float r = 0.f, c2 = 0.f, n2 = 0.f, c3 = 0.f;
        #pragma unroll
        for (int w = 0; w < 4; ++w) { r += red[w][0]; c2 += red[w][1]; n2 += red[w][2]; c3 += red[w][3]; }
        float total = c3 + L_NOOBJ * n2 + L_COORD * r + c2;
        out[0] = total * inv_n;
        out[1] = r  * inv_n;
        out[2] = c2 * inv_n;
        out[3] = n2 * inv_n;
        out[4] = c3 * inv_n;
    }
}

extern "C" void kernel_launch(void* const* d_in, const int* in_sizes, int n_in,
                              void* d_out, int out_size, void* d_ws, size_t ws_size,
                              hipStream_t stream) {
    const float* pred = (const float*)d_in[0];
    const float* tbox = (const float*)d_in[1];
    const float* tcls = (const float*)d_in[2];
    const void*  mask = d_in[3];
    const int ncells = in_sizes[3];            // N*S*S = 1,605,632
    const int N = ncells / (14 * 14);
    const int nblocks = (ncells + CHUNK - 1) / CHUNK;   // 1568

    float4* partials = (float4*)d_ws;

    yolo_loss_kernel<<<nblocks, BLK, 0, stream>>>(pred, tbox, tcls, mask,
                                                  partials, ncells);

    reduce_kernel<<<1, 256, 0, stream>>>(partials, nblocks, (float*)d_out, 1.0f / (float)N);
}

// Round 8
// 51.340 us; speedup vs baseline: 1.7658x; 1.1038x over previous
//
#include <hip/hip_runtime.h>

// YOLO loss: N=8192, S=14, B=2, C=20. ncells = N*S*S = 1,605,632.
// d_in[0] pred (ncells*30 f32), d_in[1] tbox (ncells*4 f32),
// d_in[2] tcls (ncells*20 f32), d_in[3] mask (ncells, dtype detected per block)
// d_out: 5 f32 = [total, reg, contain, noobj, cls] / N
//
// R8: discriminating experiment "issue-bound vs line-bound".
// Inactive cells (85%): ONLY 2 conf dwords (words 4,9 of the row).
// Active cells (15%): full R6 aligned-window path under the branch.
// CPT=2 (3136 blocks). Epilogue: per-block partial + reduce kernel (proven).

#define L_COORD 5.0f
#define L_NOOBJ 0.5f
#define BLK 256
#define CPT 2
#define CHUNK (BLK * CPT)   // 512 cells per block -> 3136 blocks

__launch_bounds__(256)
__global__ void yolo_loss_kernel(const float* __restrict__ pred,
                                 const float* __restrict__ tbox,
                                 const float* __restrict__ tcls,
                                 const void* __restrict__ mask,
                                 float4* __restrict__ partials,
                                 int ncells) {
    __shared__ float red[4][4];
    __shared__ int s_vote;

    const float invS = 1.0f / 14.0f;
    const unsigned tid = threadIdx.x;
    const unsigned base = blockIdx.x * CHUNK;
    const unsigned int* mw = (const unsigned int*)mask;

    // ---- per-block mask dtype classification (word {0,1}/{0,1.0f} vs byte) ----
    if (tid == 0) s_vote = 0;
    __syncthreads();
    {
        int maxw = (ncells >> 2) - 64;
        int ws = (int)(base >> 2);
        if (ws > maxw) ws = maxw;
        if (ws < 0) ws = 0;
        unsigned v = mw[ws + (tid & 63)];
        bool byteEvid = ((v & 0x01010100u) != 0u) && ((v & ~0x01010101u) == 0u);
        if (byteEvid) atomicOr(&s_vote, 1);
    }
    __syncthreads();
    const bool isByte = (s_vote & 1);

    float a_reg = 0.f, a_con = 0.f, a_noo = 0.f, a_cls = 0.f;

    // ---- phase 1: masks for CPT cells (coalesced) ----
    float fm[CPT];
    bool valid[CPT];
    #pragma unroll
    for (int k = 0; k < CPT; ++k) {
        unsigned c = base + tid + k * BLK;
        valid[k] = (c < (unsigned)ncells);
        unsigned cs = valid[k] ? c : 0u;
        if (isByte) fm[k] = (((const unsigned char*)mask)[cs] != 0) ? 1.0f : 0.0f;
        else        fm[k] = (mw[cs] != 0u) ? 1.0f : 0.0f;
    }

    // ---- phase 2: per-cell work; inactive = 2 dwords only ----
    #pragma unroll
    for (int k = 0; k < CPT; ++k) {
        if (!valid[k]) continue;
        unsigned c = base + tid + k * BLK;
        const float* row = pred + (size_t)c * 30u;

        if (fm[k] == 0.0f) {
            // noobj only: conf words 4 and 9
            float cf0 = row[4], cf1 = row[9];
            a_noo += cf0 * cf0 + cf1 * cf1;
        } else {
            // ---- full active path (R6 proven windows, all within the row) ----
            unsigned off = c * 120u;
            unsigned a = off & ~15u;
            bool sh = (off != a);
            const float4* pa4 = (const float4*)((const char*)pred + a);
            float4 q0 = pa4[0], q1 = pa4[1], q2 = pa4[2];

            float px0 = sh ? q0.z : q0.x;
            float py0 = sh ? q0.w : q0.y;
            float pw0 = sh ? q1.x : q0.z;
            float ph0 = sh ? q1.y : q0.w;
            float cf0 = sh ? q1.z : q1.x;
            float px1 = sh ? q1.w : q1.y;
            float py1 = sh ? q2.x : q1.z;
            float pw1 = sh ? q2.y : q1.w;
            float ph1 = sh ? q2.z : q2.x;
            float cf1 = sh ? q2.w : q2.y;

            unsigned off2 = off + 40u;
            unsigned a2 = off2 & ~15u;
            bool s2c = (off2 != a2);
            const float4* ca4 = (const float4*)((const char*)pred + a2);
            float W[22];
            {
                float4 u0 = ca4[0], u1 = ca4[1], u2 = ca4[2], u3 = ca4[3], u4 = ca4[4];
                W[0]=u0.x; W[1]=u0.y; W[2]=u0.z; W[3]=u0.w;
                W[4]=u1.x; W[5]=u1.y; W[6]=u1.z; W[7]=u1.w;
                W[8]=u2.x; W[9]=u2.y; W[10]=u2.z; W[11]=u2.w;
                W[12]=u3.x; W[13]=u3.y; W[14]=u3.z; W[15]=u3.w;
                W[16]=u4.x; W[17]=u4.y; W[18]=u4.z; W[19]=u4.w;
                W[20] = 0.f; W[21] = 0.f;
                if (s2c) {
                    float2 e = *(const float2*)((const char*)pred + a2 + 80u);
                    W[20] = e.x; W[21] = e.y;
                }
            }

            const float4* tc4 = (const float4*)((const char*)tcls + c * 80u);
            float cl = 0.f;
            #pragma unroll
            for (int i = 0; i < 5; ++i) {
                float4 t = tc4[i];
                float p0 = s2c ? W[4*i+2] : W[4*i+0];
                float p1 = s2c ? W[4*i+3] : W[4*i+1];
                float p2 = s2c ? W[4*i+4] : W[4*i+2];
                float p3 = s2c ? W[4*i+5] : W[4*i+3];
                float d0 = p0 - t.x, d1 = p1 - t.y, d2 = p2 - t.z, d3 = p3 - t.w;
                cl += d0 * d0 + d1 * d1 + d2 * d2 + d3 * d3;
            }
            a_cls += cl;

            float4 tb = *(const float4*)((const char*)tbox + c * 16u);
            float tx1 = tb.x * invS - 0.5f * tb.z;
            float ty1 = tb.y * invS - 0.5f * tb.w;
            float tx2 = tb.x * invS + 0.5f * tb.z;
            float ty2 = tb.y * invS + 0.5f * tb.w;
            float ta  = (tx2 - tx1) * (ty2 - ty1);

            float x1 = px0 * invS - 0.5f * pw0, y1 = py0 * invS - 0.5f * ph0;
            float x2 = px0 * invS + 0.5f * pw0, y2 = py0 * invS + 0.5f * ph0;
            float lx = fmaxf(x1, tx1), ly = fmaxf(y1, ty1);
            float rx = fminf(x2, tx2), ry = fminf(y2, ty2);
            float wx = fmaxf(rx - lx, 0.f), wy = fmaxf(ry - ly, 0.f);
            float inter = wx * wy;
            float pa = (x2 - x1) * (y2 - y1);
            float iou0 = inter / (pa + ta - inter);

            x1 = px1 * invS - 0.5f * pw1; y1 = py1 * invS - 0.5f * ph1;
            x2 = px1 * invS + 0.5f * pw1; y2 = py1 * invS + 0.5f * ph1;
            lx = fmaxf(x1, tx1); ly = fmaxf(y1, ty1);
            rx = fminf(x2, tx2); ry = fminf(y2, ty2);
            wx = fmaxf(rx - lx, 0.f); wy = fmaxf(ry - ly, 0.f);
            inter = wx * wy;
            pa = (x2 - x1) * (y2 - y1);
            float iou1 = inter / (pa + ta - inter);

            // jnp.argmax: first index on tie -> box1 wins only if strictly greater
            int best = (iou1 > iou0) ? 1 : 0;
            float miou = fmaxf(iou0, iou1);

            float bx = best ? px1 : px0, by = best ? py1 : py0;
            float bw = best ? pw1 : pw0, bh = best ? ph1 : ph0;
            float bc = best ? cf1 : cf0;

            float dx = bx - tb.x, dy = by - tb.y;
            float sw = sqrtf(fmaxf(bw, 0.f)) - sqrtf(fmaxf(tb.z, 0.f));
            float sh2 = sqrtf(fmaxf(bh, 0.f)) - sqrtf(fmaxf(tb.w, 0.f));
            a_reg += dx * dx + dy * dy + sw * sw + sh2 * sh2;
            float dc = bc - miou;
            a_con += dc * dc;
        }
    }

    // ---- wave reduce, block reduce, ONE uncontended partial store ----
    #pragma unroll
    for (int off = 32; off > 0; off >>= 1) {
        a_reg += __shfl_down(a_reg, off, 64);
        a_con += __shfl_down(a_con, off, 64);
        a_noo += __shfl_down(a_noo, off, 64);
        a_cls += __shfl_down(a_cls, off, 64);
    }
    const int wid = threadIdx.x >> 6, lane = threadIdx.x & 63;
    if (lane == 0) {
        red[wid][0] = a_reg; red[wid][1] = a_con;
        red[wid][2] = a_noo; red[wid][3] = a_cls;
    }
    __syncthreads();
    if (threadIdx.x == 0) {
        float rg = 0.f, co = 0.f, no = 0.f, cl = 0.f;
        #pragma unroll
        for (int w = 0; w < 4; ++w) {
            rg += red[w][0]; co += red[w][1]; no += red[w][2]; cl += red[w][3];
        }
        partials[blockIdx.x] = make_float4(rg, co, no, cl);
    }
}

__launch_bounds__(256)
__global__ void reduce_kernel(const float4* __restrict__ partials, int nblocks,
                              float* __restrict__ out, float inv_n) {
    __shared__ float red[4][4];
    float rg = 0.f, co = 0.f, no = 0.f, cl = 0.f;
    for (int i = threadIdx.x; i < nblocks; i += blockDim.x) {
        float4 p = partials[i];
        rg += p.x; co += p.y; no += p.z; cl += p.w;
    }
    #pragma unroll
    for (int off = 32; off > 0; off >>= 1) {
        rg += __shfl_down(rg, off, 64);
        co += __shfl_down(co, off, 64);
        no += __shfl_down(no, off, 64);
        cl += __shfl_down(cl, off, 64);
    }
    const int wid = threadIdx.x >> 6, lane = threadIdx.x & 63;
    if (lane == 0) { red[wid][0] = rg; red[wid][1] = co; red[wid][2] = no; red[wid][3] = cl; }
    __syncthreads();
    if (threadIdx.x == 0) {
        float r = 0.f, c2 = 0.f, n2 = 0.f, c3 = 0.f;
        #pragma unroll
        for (int w = 0; w < 4; ++w) { r += red[w][0]; c2 += red[w][1]; n2 += red[w][2]; c3 += red[w][3]; }
        float total = c3 + L_NOOBJ * n2 + L_COORD * r + c2;
        out[0] = total * inv_n;
        out[1] = r  * inv_n;
        out[2] = c2 * inv_n;
        out[3] = n2 * inv_n;
        out[4] = c3 * inv_n;
    }
}

extern "C" void kernel_launch(void* const* d_in, const int* in_sizes, int n_in,
                              void* d_out, int out_size, void* d_ws, size_t ws_size,
                              hipStream_t stream) {
    const float* pred = (const float*)d_in[0];
    const float* tbox = (const float*)d_in[1];
    const float* tcls = (const float*)d_in[2];
    const void*  mask = d_in[3];
    const int ncells = in_sizes[3];            // N*S*S = 1,605,632
    const int N = ncells / (14 * 14);
    const int nblocks = (ncells + CHUNK - 1) / CHUNK;   // 3136

    float4* partials = (float4*)d_ws;

    yolo_loss_kernel<<<nblocks, BLK, 0, stream>>>(pred, tbox, tcls, mask,
                                                  partials, ncells);

    reduce_kernel<<<1, 256, 0, stream>>>(partials, nblocks, (float*)d_out, 1.0f / (float)N);
}